// Round 18
// baseline (645.465 us; speedup 1.0000x reference)
//
#include <hip/hip_runtime.h>
#include <hip/hip_bf16.h>
#include <hip/hip_fp16.h>

#define NNODES 60000
#define NREL   70
#define NB     30
#define NEDGE  1920000
#define NBLK   235      // ceil(NNODES/256)
#define W2P    328      // padded et-stride (halves): 8 outputs x 40 + 8 pad (bank-shifts et rows)

typedef _Float16 half2v __attribute__((ext_vector_type(2)));

static __device__ __forceinline__ float fdot2f(unsigned a, unsigned b, float c) {
    return __builtin_amdgcn_fdot2(__builtin_bit_cast(half2v, a),
                                  __builtin_bit_cast(half2v, b), c, false);
}
static __device__ __forceinline__ unsigned pack2h(float lo, float hi) {
    __half2 h = __floats2half2_rn(lo, hi);
    return *reinterpret_cast<unsigned*>(&h);
}

// ---------------- CSR build, stream path: 4-way replicated counters ----------------
// rank packing: rS(14) | repS(2)<<14 | rD(14)<<16 | repD(2)<<30

__global__ void hist2_rep_kernel(const int* __restrict__ src, const int* __restrict__ dst,
                                 int* __restrict__ cntS4, int* __restrict__ cntD4,
                                 int* __restrict__ ranks) {
    int e = blockIdx.x * blockDim.x + threadIdx.x;
    if (e < NEDGE) {
        int repS = e & 3, repD = (e >> 2) & 3;
        int rS = atomicAdd(&cntS4[repS * NNODES + src[e]], 1);
        int rD = atomicAdd(&cntD4[repD * NNODES + dst[e]], 1);
        ranks[e] = rS | (repS << 14) | (rD << 16) | (repD << 30);
    }
}

// fold replicas -> totals + uchar4 prefix bases (per-replica prefix < 256)
__global__ void totals_kernel(const int* __restrict__ cntS4, const int* __restrict__ cntD4,
                              int* __restrict__ cntS, int* __restrict__ cntD,
                              unsigned* __restrict__ baseS, unsigned* __restrict__ baseD) {
    int n = blockIdx.x * 256 + threadIdx.x;
    if (n >= NNODES) return;
    int s0 = cntS4[n], s1 = cntS4[NNODES + n], s2 = cntS4[2 * NNODES + n], s3 = cntS4[3 * NNODES + n];
    cntS[n] = s0 + s1 + s2 + s3;
    baseS[n] = ((unsigned)s0 << 8) | ((unsigned)(s0 + s1) << 16) | ((unsigned)(s0 + s1 + s2) << 24);
    int d0 = cntD4[n], d1 = cntD4[NNODES + n], d2 = cntD4[2 * NNODES + n], d3 = cntD4[3 * NNODES + n];
    cntD[n] = d0 + d1 + d2 + d3;
    baseD[n] = ((unsigned)d0 << 8) | ((unsigned)(d0 + d1) << 16) | ((unsigned)(d0 + d1 + d2) << 24);
}

// ---------------- CSR build, fallback path (old, un-replicated) ----------------

__global__ void hist2_kernel(const int* __restrict__ src, const int* __restrict__ dst,
                             int* __restrict__ cntS, int* __restrict__ cntD,
                             int* __restrict__ ranks) {
    int e = blockIdx.x * blockDim.x + threadIdx.x;
    if (e < NEDGE) {
        int rS = atomicAdd(&cntS[src[e]], 1);
        int rD = atomicAdd(&cntD[dst[e]], 1);
        ranks[e] = (rD << 16) | rS;
    }
}

// fused hierarchical exclusive scan over BOTH cnt arrays
__global__ void scanA2_kernel(const int* __restrict__ cntS, const int* __restrict__ cntD,
                              int* __restrict__ bsum) {
    __shared__ int lds[256];
    int half = (blockIdx.x >= NBLK) ? 1 : 0;
    int blk  = blockIdx.x - half * NBLK;
    const int* cnt = half ? cntD : cntS;
    int i = blk * 256 + threadIdx.x;
    int v = (i < NNODES) ? cnt[i] : 0;
    lds[threadIdx.x] = v;
    __syncthreads();
    for (int d = 128; d > 0; d >>= 1) {
        if (threadIdx.x < d) lds[threadIdx.x] += lds[threadIdx.x + d];
        __syncthreads();
    }
    if (threadIdx.x == 0) bsum[half * 256 + blk] = lds[0];
}

__global__ void scanB2_kernel(const int* __restrict__ bsum, int* __restrict__ boff) {
    __shared__ int lds[256];
    for (int half = 0; half < 2; ++half) {
        int v = (threadIdx.x < NBLK) ? bsum[half * 256 + threadIdx.x] : 0;
        lds[threadIdx.x] = v;
        __syncthreads();
        for (int d = 1; d < 256; d <<= 1) {
            int t = (threadIdx.x >= d) ? lds[threadIdx.x - d] : 0;
            __syncthreads();
            lds[threadIdx.x] += t;
            __syncthreads();
        }
        boff[half * 256 + threadIdx.x] = lds[threadIdx.x] - v;   // exclusive
        __syncthreads();
    }
}

__global__ void scanC2_kernel(const int* __restrict__ cntS, const int* __restrict__ cntD,
                              const int* __restrict__ boff,
                              int* __restrict__ offsS, int* __restrict__ offsD) {
    __shared__ int lds[256];
    int half = (blockIdx.x >= NBLK) ? 1 : 0;
    int blk  = blockIdx.x - half * NBLK;
    const int* cnt = half ? cntD : cntS;
    int* offs = half ? offsD : offsS;
    int i = blk * 256 + threadIdx.x;
    int v = (i < NNODES) ? cnt[i] : 0;
    lds[threadIdx.x] = v;
    __syncthreads();
    for (int d = 1; d < 256; d <<= 1) {
        int t = (threadIdx.x >= d) ? lds[threadIdx.x - d] : 0;
        __syncthreads();
        lds[threadIdx.x] += t;
        __syncthreads();
    }
    if (i < NNODES) offs[i] = boff[half * 256 + blk] + lds[threadIdx.x] - v;
}

// stream mode: no atomics — replicated ranks + prefix bases.
__global__ void fill2_stream_kernel(const int* __restrict__ src, const int* __restrict__ dst,
                                    const int* __restrict__ et, const int* __restrict__ ranks,
                                    const int* __restrict__ offsS, const int* __restrict__ offsD,
                                    const unsigned* __restrict__ baseS, const unsigned* __restrict__ baseD,
                                    int2* __restrict__ ebufSD) {
    int e = blockIdx.x * blockDim.x + threadIdx.x;
    if (e < NEDGE) {
        int s = src[e], d = dst[e], t = et[e];
        unsigned r = (unsigned)ranks[e];
        int rS = r & 0x3FFF, repS = (r >> 14) & 3;
        int rD = (r >> 16) & 0x3FFF, repD = r >> 30;
        int spos = offsS[s] + ((baseS[s] >> (8 * repS)) & 0xFF) + rS;
        int slot = offsD[d] + ((baseD[d] >> (8 * repD)) & 0xFF) + rD;
        ebufSD[spos] = make_int2((t << 25) | slot, (t << 16) | d);
    }
}

// atomic (fallback) mode, old rank packing
__global__ void fill2_atomic_kernel(const int* __restrict__ src, const int* __restrict__ dst,
                                    const int* __restrict__ et, const int* __restrict__ ranks,
                                    const int* __restrict__ offsS, const int* __restrict__ offsD,
                                    int* __restrict__ ebufS, int* __restrict__ ebufD) {
    int e = blockIdx.x * blockDim.x + threadIdx.x;
    if (e < NEDGE) {
        int s = src[e], d = dst[e], t = et[e];
        int r = ranks[e];
        ebufD[offsD[d] + (r >> 16)]   = (t << 16) | s;
        ebufS[offsS[s] + (r & 0xFFFF)] = (t << 16) | d;
    }
}

// ---------------- weight expansion ----------------

__global__ void wexpand2_kernel(const float* __restrict__ att, const float* __restrict__ basis,
                                float* __restrict__ w2t) {
    int idx = blockIdx.x * blockDim.x + threadIdx.x;
    if (idx >= NREL * 256) return;
    int r = idx >> 8, t = idx & 255, o = t >> 5, i = t & 31;
    float s = 0.f;
    #pragma unroll
    for (int b = 0; b < NB; ++b) s += att[r * NB + b] * basis[b * 256 + i * 8 + o];
    w2t[r * 256 + o * 32 + i] = s;
}

// fp16 padded w2h[r*W2P + o*40 + i], o<8, i<32 real, rest 0
__global__ void wexpand2h_kernel(const float* __restrict__ att, const float* __restrict__ basis,
                                 unsigned short* __restrict__ w2h) {
    int idx = blockIdx.x * blockDim.x + threadIdx.x;
    if (idx >= NREL * W2P) return;
    int r = idx / W2P, t = idx - r * W2P;
    int o = t / 40, i = t - o * 40;
    float s = 0.f;
    if (o < 8 && i < 32) {
        #pragma unroll
        for (int b = 0; b < NB; ++b) s += att[r * NB + b] * basis[b * 256 + i * 8 + o];
    }
    w2h[idx] = __half_as_ushort(__float2half_rn(s));
}

__global__ void wexpand3_kernel(const float* __restrict__ att, const float* __restrict__ basis,
                                float* __restrict__ w3) {
    int idx = blockIdx.x * blockDim.x + threadIdx.x;
    if (idx >= NREL * 8) return;
    int r = idx >> 3, i = idx & 7;
    float s = 0.f;
    #pragma unroll
    for (int b = 0; b < NB; ++b) s += att[r * NB + b] * basis[b * 8 + i];
    w3[idx] = s;
}

// ---------------- layer 1, stream path (fp16 fdot2) ----------------

__global__ void layer1_scatter_stream_kernel(const int2* __restrict__ ebufSD,
                                             const int* __restrict__ offsS,
                                             const int* __restrict__ cntS,
                                             const float* __restrict__ att1,
                                             const float* __restrict__ basis1,
                                             unsigned short* __restrict__ msgh) {
    __shared__ unsigned att_lds[NREL * 16];   // [r][16] half2-packed, pair 15 = 0
    for (int i = threadIdx.x; i < NREL * 16; i += 256) {
        int r = i >> 4, j = i & 15;
        float lo = (2 * j     < NB) ? att1[r * NB + 2 * j]     : 0.f;
        float hi = (2 * j + 1 < NB) ? att1[r * NB + 2 * j + 1] : 0.f;
        att_lds[i] = pack2h(lo, hi);
    }
    __syncthreads();
    int wave = threadIdx.x >> 6, lane = threadIdx.x & 63;
    int s = blockIdx.x * 4 + wave;           // NNODES % 4 == 0
    int o = lane & 31, half = lane >> 5;
    int off = offsS[s], c = cntS[s];
    if (c == 0) return;
    float Bf[NB];
    const float* bp = basis1 + (size_t)s * 32 + o;
    #pragma unroll
    for (int b = 0; b < NB; ++b) Bf[b] = bp[(size_t)b * (NNODES * 32)];
    unsigned B2[16];
    #pragma unroll
    for (int q = 0; q < 15; ++q) B2[q] = pack2h(Bf[2 * q], Bf[2 * q + 1]);
    B2[15] = 0u;
    for (int k = half; k < c; k += 2) {
        unsigned p = (unsigned)ebufSD[off + k].x;
        int slot = p & 0x01FFFFFF;
        int et   = p >> 25;
        const uint4* ar = (const uint4*)(att_lds + et * 16);
        float m0 = 0.f, m1 = 0.f, m2 = 0.f, m3 = 0.f;
        #pragma unroll
        for (int q = 0; q < 4; ++q) {
            uint4 w = ar[q];
            m0 = fdot2f(w.x, B2[q * 4 + 0], m0);
            m1 = fdot2f(w.y, B2[q * 4 + 1], m1);
            m2 = fdot2f(w.z, B2[q * 4 + 2], m2);
            m3 = fdot2f(w.w, B2[q * 4 + 3], m3);
        }
        float m = (m0 + m1) + (m2 + m3);
        float mo = __shfl_xor(m, 1);
        if ((o & 1) == 0) {
            __half2 h;
            h.x = __float2half_rn(m);
            h.y = __float2half_rn(mo);
            *reinterpret_cast<__half2*>(msgh + (size_t)slot * 32 + o) = h;
        }
    }
}

// reduce: 8 slots in flight, 8B loads/lane, float4 store
__global__ void layer1_reduce_kernel(const unsigned short* __restrict__ msgh,
                                     const int* __restrict__ offsD, const int* __restrict__ cntD,
                                     const float* __restrict__ root1,
                                     const float* __restrict__ bias1,
                                     float* __restrict__ x1) {
    int wave = threadIdx.x >> 6, lane = threadIdx.x & 63;
    int n = blockIdx.x * 4 + wave;
    int o4 = (lane & 7) * 4, grp = lane >> 3;
    int off = offsD[n], c = cntD[n];
    float a0 = 0.f, a1 = 0.f, a2 = 0.f, a3 = 0.f;
    for (int k = grp; k < c; k += 8) {
        uint2 u = *reinterpret_cast<const uint2*>(msgh + (size_t)(off + k) * 32 + o4);
        __half2 h0 = *reinterpret_cast<__half2*>(&u.x);
        __half2 h1 = *reinterpret_cast<__half2*>(&u.y);
        float2 f0 = __half22float2(h0), f1 = __half22float2(h1);
        a0 += f0.x; a1 += f0.y; a2 += f1.x; a3 += f1.y;
    }
    a0 += __shfl_xor(a0, 8);  a1 += __shfl_xor(a1, 8);  a2 += __shfl_xor(a2, 8);  a3 += __shfl_xor(a3, 8);
    a0 += __shfl_xor(a0, 16); a1 += __shfl_xor(a1, 16); a2 += __shfl_xor(a2, 16); a3 += __shfl_xor(a3, 16);
    a0 += __shfl_xor(a0, 32); a1 += __shfl_xor(a1, 32); a2 += __shfl_xor(a2, 32); a3 += __shfl_xor(a3, 32);
    if (grp == 0) {
        float inv = 1.0f / fmaxf((float)c, 1.0f);
        size_t base = (size_t)n * 32 + o4;
        float4 r = *reinterpret_cast<const float4*>(root1 + base);
        float4 v;
        v.x = fmaxf(a0 * inv + r.x + bias1[o4],     0.f);
        v.y = fmaxf(a1 * inv + r.y + bias1[o4 + 1], 0.f);
        v.z = fmaxf(a2 * inv + r.z + bias1[o4 + 2], 0.f);
        v.w = fmaxf(a3 * inv + r.w + bias1[o4 + 3], 0.f);
        *reinterpret_cast<float4*>(x1 + base) = v;
    }
}

// ---------------- layer 1, atomic fallback ----------------

__global__ void layer1_scatter_kernel(const int* __restrict__ ebufS, const int* __restrict__ offsS,
                                      const int* __restrict__ cntS, const float* __restrict__ att1,
                                      const float* __restrict__ basis1, float* __restrict__ x1acc) {
    int wave = threadIdx.x >> 6, lane = threadIdx.x & 63;
    int s = blockIdx.x * 4 + wave;
    int o = lane & 31, half = lane >> 5;
    int off = offsS[s], c = cntS[s];
    if (c == 0) return;
    float B[NB];
    const float* bp = basis1 + (size_t)s * 32 + o;
    #pragma unroll
    for (int b = 0; b < NB; ++b) B[b] = bp[(size_t)b * (NNODES * 32)];
    for (int k = half; k < c; k += 2) {
        int p  = ebufS[off + k];
        int d  = p & 0xFFFF, et = p >> 16;
        float attv = (o < NB) ? att1[et * NB + o] : 0.f;
        float m = 0.f;
        #pragma unroll
        for (int b = 0; b < NB; ++b) {
            float a = __shfl(attv, (lane & 32) + b);
            m = fmaf(a, B[b], m);
        }
        atomicAdd(&x1acc[(size_t)d * 32 + o], m);
    }
}

__global__ void layer1_finalize_kernel(const int* __restrict__ cntD,
                                       const float* __restrict__ root1,
                                       const float* __restrict__ bias1,
                                       float* __restrict__ x1) {
    int i = blockIdx.x * 256 + threadIdx.x;
    if (i >= NNODES * 32) return;
    int n = i >> 5, o = i & 31;
    float c = (float)cntD[n];
    float v = x1[i] / fmaxf(c, 1.0f) + root1[i] + bias1[o];
    x1[i] = fmaxf(v, 0.0f);
}

// ---------------- layer 2: src-major, LDS fp16 weights, atomic accumulate ----------------

__global__ void layer2_src_atomic_kernel(const int2* __restrict__ ebufSD,
                                         const int* __restrict__ offsS, const int* __restrict__ cntS,
                                         const float* __restrict__ x1,
                                         const unsigned short* __restrict__ w2h,
                                         float* __restrict__ x2acc) {
    __shared__ unsigned short w2l[NREL * W2P];   // 45,920 B
    for (int i = threadIdx.x; i < NREL * W2P; i += 1024) w2l[i] = w2h[i];
    __syncthreads();
    int wave = threadIdx.x >> 6, lane = threadIdx.x & 63;
    int s = blockIdx.x * 16 + wave;          // NNODES % 16 == 0
    int o = lane & 7, grp = lane >> 3;
    int off = offsS[s], c = cntS[s];
    if (c == 0) return;
    float2 xf[16];
    const float2* xp2 = (const float2*)(x1 + (size_t)s * 32);
    #pragma unroll
    for (int i = 0; i < 16; ++i) xf[i] = xp2[i];
    for (int k0 = 0; k0 < c; k0 += 8) {
        int kk = k0 + grp;
        if (kk < c) {
            int p = ebufSD[off + kk].y;
            int d = p & 0xFFFF, et = p >> 16;
            const unsigned short* wp = w2l + et * W2P + o * 40;
            float a0 = 0.f, a1 = 0.f, a2 = 0.f, a3 = 0.f;
            #pragma unroll
            for (int q = 0; q < 4; ++q) {
                uint4 wv = *reinterpret_cast<const uint4*>(wp + q * 8);
                __half2 h; float2 f;
                h = *reinterpret_cast<const __half2*>(&wv.x); f = __half22float2(h);
                a0 = fmaf(xf[q * 4 + 0].x, f.x, a0); a0 = fmaf(xf[q * 4 + 0].y, f.y, a0);
                h = *reinterpret_cast<const __half2*>(&wv.y); f = __half22float2(h);
                a1 = fmaf(xf[q * 4 + 1].x, f.x, a1); a1 = fmaf(xf[q * 4 + 1].y, f.y, a1);
                h = *reinterpret_cast<const __half2*>(&wv.z); f = __half22float2(h);
                a2 = fmaf(xf[q * 4 + 2].x, f.x, a2); a2 = fmaf(xf[q * 4 + 2].y, f.y, a2);
                h = *reinterpret_cast<const __half2*>(&wv.w); f = __half22float2(h);
                a3 = fmaf(xf[q * 4 + 3].x, f.x, a3); a3 = fmaf(xf[q * 4 + 3].y, f.y, a3);
            }
            float acc = (a0 + a1) + (a2 + a3);
            atomicAdd(&x2acc[(size_t)d * 8 + o], acc);
        }
    }
}

__global__ void layer2_finalize_kernel(const int* __restrict__ cntD,
                                       const float* __restrict__ x1,
                                       const float* __restrict__ root2,
                                       const float* __restrict__ bias2,
                                       float* __restrict__ x2) {
    int t = blockIdx.x * 256 + threadIdx.x;
    if (t >= NNODES * 8) return;
    int n = t >> 3, o = t & 7;
    float self = 0.f;
    const float* xn = x1 + (size_t)n * 32;
    #pragma unroll
    for (int i = 0; i < 32; ++i) self = fmaf(xn[i], root2[i * 8 + o], self);
    float c = (float)cntD[n];
    float v = x2[t] / fmaxf(c, 1.0f) + self + bias2[o];
    x2[t] = fmaxf(v, 0.0f);
}

// ---------------- layer 3: src-major, LDS weights, atomic accumulate into d_out ----------------

__global__ void layer3_src_atomic_kernel(const int2* __restrict__ ebufSD,
                                         const int* __restrict__ offsS, const int* __restrict__ cntS,
                                         const float* __restrict__ x2, const float* __restrict__ w3,
                                         float* __restrict__ outacc) {
    __shared__ float w3l[NREL * 8];
    for (int i = threadIdx.x; i < NREL * 8; i += 256) w3l[i] = w3[i];
    __syncthreads();
    int wave = threadIdx.x >> 6, lane = threadIdx.x & 63;
    int s = blockIdx.x * 4 + wave;
    int off = offsS[s], c = cntS[s];
    if (c == 0) return;
    const float4* xp = (const float4*)(x2 + (size_t)s * 8);
    float4 a0 = xp[0], a1 = xp[1];
    for (int k = lane; k < c; k += 64) {
        int p = ebufSD[off + k].y;
        int d = p & 0xFFFF, et = p >> 16;
        const float4* wp = (const float4*)(w3l + et * 8);
        float4 b0 = wp[0], b1 = wp[1];
        float m = a0.x * b0.x + a0.y * b0.y + a0.z * b0.z + a0.w * b0.w
                + a1.x * b1.x + a1.y * b1.y + a1.z * b1.z + a1.w * b1.w;
        atomicAdd(&outacc[d], m);
    }
}

__global__ void layer3_finalize_kernel(const int* __restrict__ cntD,
                                       const float* __restrict__ x2,
                                       const float* __restrict__ root3,
                                       const float* __restrict__ bias3,
                                       float* __restrict__ out) {
    int n = blockIdx.x * 256 + threadIdx.x;
    if (n >= NNODES) return;
    float self = 0.f;
    const float* xn = x2 + (size_t)n * 8;
    #pragma unroll
    for (int i = 0; i < 8; ++i) self = fmaf(xn[i], root3[i], self);
    float c = (float)cntD[n];
    out[n] = out[n] / fmaxf(c, 1.0f) + self + bias3[0];
}

// ---------------- legacy per-node layers 2/3 (fallback, atomic-mode only) ----------------

__global__ void layer2_kernel(const int* __restrict__ ebufD, const int* __restrict__ offsD,
                              const int* __restrict__ cntD,
                              const float* __restrict__ x1, const float* __restrict__ w2t,
                              const float* __restrict__ root2, const float* __restrict__ bias2,
                              float* __restrict__ x2) {
    int wave = threadIdx.x >> 6, lane = threadIdx.x & 63;
    int n = blockIdx.x * 4 + wave;
    int o = lane & 7, slot = lane >> 3;
    int off = offsD[n], c = cntD[n];
    float acc = 0.f;
    for (int k0 = 0; k0 < c; k0 += 8) {
        int kk = k0 + slot;
        if (kk < c) {
            int packed = ebufD[off + kk];
            int src = packed & 0xFFFF, et = packed >> 16;
            const float4* xp = (const float4*)(x1 + (size_t)src * 32);
            const float4* wp = (const float4*)(w2t + et * 256 + o * 32);
            #pragma unroll
            for (int i = 0; i < 8; ++i) {
                float4 xv = xp[i], wv = wp[i];
                acc += xv.x * wv.x + xv.y * wv.y + xv.z * wv.z + xv.w * wv.w;
            }
        }
    }
    #pragma unroll
    for (int d = 8; d < 64; d <<= 1) acc += __shfl_xor(acc, d);
    if (lane < 8) {
        float self = 0.f;
        const float* xn = x1 + (size_t)n * 32;
        #pragma unroll
        for (int i = 0; i < 32; ++i) self += xn[i] * root2[i * 8 + o];
        float v = acc / fmaxf((float)c, 1.0f) + self + bias2[o];
        x2[(size_t)n * 8 + o] = fmaxf(v, 0.0f);
    }
}

__global__ void layer3_kernel(const int* __restrict__ ebufD, const int* __restrict__ offsD,
                              const int* __restrict__ cntD,
                              const float* __restrict__ x2, const float* __restrict__ w3,
                              const float* __restrict__ root3, const float* __restrict__ bias3,
                              float* __restrict__ out) {
    int wave = threadIdx.x >> 6, lane = threadIdx.x & 63;
    int n = blockIdx.x * 4 + wave;
    int off = offsD[n], c = cntD[n];
    float acc = 0.f;
    for (int k = lane; k < c; k += 64) {
        int packed = ebufD[off + k];
        int src = packed & 0xFFFF, et = packed >> 16;
        const float4* xp = (const float4*)(x2 + src * 8);
        const float4* wp = (const float4*)(w3 + et * 8);
        float4 a0 = xp[0], a1 = xp[1], b0 = wp[0], b1 = wp[1];
        acc += a0.x * b0.x + a0.y * b0.y + a0.z * b0.z + a0.w * b0.w
             + a1.x * b1.x + a1.y * b1.y + a1.z * b1.z + a1.w * b1.w;
    }
    #pragma unroll
    for (int d = 1; d < 64; d <<= 1) acc += __shfl_xor(acc, d);
    if (lane == 0) {
        float self = 0.f;
        const float* xn = x2 + (size_t)n * 8;
        #pragma unroll
        for (int i = 0; i < 8; ++i) self += xn[i] * root3[i];
        out[n] = acc / fmaxf((float)c, 1.0f) + self + bias3[0];
    }
}

// ---------------- launch ----------------

extern "C" void kernel_launch(void* const* d_in, const int* in_sizes, int n_in,
                              void* d_out, int out_size, void* d_ws, size_t ws_size,
                              hipStream_t stream) {
    const int*   edge_index = (const int*)  d_in[0];
    const int*   edge_type  = (const int*)  d_in[1];
    const float* att1   = (const float*) d_in[2];
    const float* basis1 = (const float*) d_in[3];
    const float* root1  = (const float*) d_in[4];
    const float* bias1  = (const float*) d_in[5];
    const float* att2   = (const float*) d_in[6];
    const float* basis2 = (const float*) d_in[7];
    const float* root2  = (const float*) d_in[8];
    const float* bias2  = (const float*) d_in[9];
    const float* att3   = (const float*) d_in[10];
    const float* basis3 = (const float*) d_in[11];
    const float* root3  = (const float*) d_in[12];
    const float* bias3  = (const float*) d_in[13];
    float* out = (float*)d_out;

    const int* srcArr = edge_index;
    const int* dstArr = edge_index + NEDGE;

    char* ws = (char*)d_ws;
    int*   cntS   = (int*)(ws + 0);              // 240,000
    int*   cntD   = (int*)(ws + 240128);         // 240,000
    int*   offsS  = (int*)(ws + 480256);         // 240,000
    int*   offsD  = (int*)(ws + 720384);         // 240,000
    int*   bsum   = (int*)(ws + 960512);         // 2,048
    int*   boff   = (int*)(ws + 962560);         // 2,048
    int*   ebufS  = (int*)(ws + 1442816);        // 7,680,000 (fallback)
    int*   ebufD  = (int*)(ws + 9122816);        // 7,680,000 (fallback)
    int2*  ebufSD = (int2*)(ws + 1442816);       // 15,360,000 (stream: combined)
    float* w2t    = (float*)(ws + 16802816);     // 71,680 (fallback)
    float* w3     = (float*)(ws + 16874496);     // 2,240
    unsigned short* w2h = (unsigned short*)(ws + 16876800);  // 45,920
    float* x1     = (float*)(ws + 16923648);     // 7,680,000
    int*   ranks  = (int*)(ws + 16923648);       // aliases x1 (dead until layer1_reduce)
    float* x2     = (float*)(ws + 24603648);     // 1,920,000  (acc then final, in place)
    unsigned* baseS = (unsigned*)(ws + 24603648);            // aliases x2 (dead after fill2)
    unsigned* baseD = (unsigned*)(ws + 24603648 + 240000);
    unsigned short* msgh = (unsigned short*)(ws + 26523648); // 122,880,000 -> end 149,403,648
    int*   cntS4  = (int*)(ws + 26523648);       // aliases msgh (dead before scatter): 960,000
    int*   cntD4  = (int*)(ws + 26523648 + 960000);          // 960,000
    const bool use_stream = ws_size >= 149403648ULL;

    hipMemsetAsync(d_out, 0, NNODES * 4, stream);       // out accumulator

    if (use_stream) {
        // CSR build with 4-way replicated counters (no same-address hotspots)
        hipMemsetAsync((void*)cntS4, 0, 1920000, stream);   // cntS4 + cntD4
        hist2_rep_kernel<<<NEDGE / 256, 256, 0, stream>>>(srcArr, dstArr, cntS4, cntD4, ranks);
        totals_kernel<<<NBLK, 256, 0, stream>>>(cntS4, cntD4, cntS, cntD, baseS, baseD);
        scanA2_kernel<<<2 * NBLK, 256, 0, stream>>>(cntS, cntD, bsum);
        scanB2_kernel<<<1, 256, 0, stream>>>(bsum, boff);
        scanC2_kernel<<<2 * NBLK, 256, 0, stream>>>(cntS, cntD, boff, offsS, offsD);
        fill2_stream_kernel<<<NEDGE / 256, 256, 0, stream>>>(srcArr, dstArr, edge_type, ranks,
                                                             offsS, offsD, baseS, baseD, ebufSD);
        hipMemsetAsync((void*)x2, 0, 1920000, stream);      // x2 accumulator (bases now dead)

        // weight expansion
        wexpand2h_kernel<<<(NREL * W2P + 255) / 256, 256, 0, stream>>>(att2, basis2, w2h);
        wexpand3_kernel<<<(NREL * 8 + 255) / 256, 256, 0, stream>>>(att3, basis3, w3);

        // layer 1
        layer1_scatter_stream_kernel<<<NNODES / 4, 256, 0, stream>>>(ebufSD, offsS, cntS,
                                                                     att1, basis1, msgh);
        layer1_reduce_kernel<<<NNODES / 4, 256, 0, stream>>>(msgh, offsD, cntD, root1, bias1, x1);

        // layers 2, 3
        layer2_src_atomic_kernel<<<NNODES / 16, 1024, 0, stream>>>(ebufSD, offsS, cntS, x1, w2h, x2);
        layer2_finalize_kernel<<<(NNODES * 8 + 255) / 256, 256, 0, stream>>>(cntD, x1, root2, bias2, x2);
        layer3_src_atomic_kernel<<<NNODES / 4, 256, 0, stream>>>(ebufSD, offsS, cntS, x2, w3, out);
        layer3_finalize_kernel<<<(NNODES + 255) / 256, 256, 0, stream>>>(cntD, x2, root3, bias3, out);
    } else {
        // fallback: old un-replicated path
        hipMemsetAsync(ws, 0, 480128, stream);              // cntS + cntD
        hipMemsetAsync((void*)x2, 0, 1920000, stream);
        hist2_kernel<<<NEDGE / 256, 256, 0, stream>>>(srcArr, dstArr, cntS, cntD, ranks);
        scanA2_kernel<<<2 * NBLK, 256, 0, stream>>>(cntS, cntD, bsum);
        scanB2_kernel<<<1, 256, 0, stream>>>(bsum, boff);
        scanC2_kernel<<<2 * NBLK, 256, 0, stream>>>(cntS, cntD, boff, offsS, offsD);
        fill2_atomic_kernel<<<NEDGE / 256, 256, 0, stream>>>(srcArr, dstArr, edge_type, ranks,
                                                             offsS, offsD, ebufS, ebufD);
        wexpand2_kernel<<<(NREL * 256 + 255) / 256, 256, 0, stream>>>(att2, basis2, w2t);
        wexpand3_kernel<<<(NREL * 8 + 255) / 256, 256, 0, stream>>>(att3, basis3, w3);
        hipMemsetAsync((void*)x1, 0, 7680000, stream);
        layer1_scatter_kernel<<<NNODES / 4, 256, 0, stream>>>(ebufS, offsS, cntS, att1, basis1, x1);
        layer1_finalize_kernel<<<(NNODES * 32) / 256, 256, 0, stream>>>(cntD, root1, bias1, x1);
        layer2_kernel<<<NNODES / 4, 256, 0, stream>>>(ebufD, offsD, cntD, x1, w2t, root2, bias2, x2);
        layer3_kernel<<<NNODES / 4, 256, 0, stream>>>(ebufD, offsD, cntD, x2, w3, root3, bias3, out);
    }
}

// Round 19
// 616.422 us; speedup vs baseline: 1.0471x; 1.0471x over previous
//
#include <hip/hip_runtime.h>
#include <hip/hip_bf16.h>
#include <hip/hip_fp16.h>

#define NNODES 60000
#define NREL   70
#define NB     30
#define NEDGE  1920000
#define NBLK   235      // ceil(NNODES/256)
#define W2P    328      // padded et-stride (halves)

typedef _Float16 half2v __attribute__((ext_vector_type(2)));

static __device__ __forceinline__ float fdot2f(unsigned a, unsigned b, float c) {
    return __builtin_amdgcn_fdot2(__builtin_bit_cast(half2v, a),
                                  __builtin_bit_cast(half2v, b), c, false);
}
static __device__ __forceinline__ unsigned pack2h(float lo, float hi) {
    __half2 h = __floats2half2_rn(lo, hi);
    return *reinterpret_cast<unsigned*>(&h);
}

// ---------------- CSR build: 8 edges/thread (MLP for atomic returns) ----------------

__global__ void hist2_kernel8(const int* __restrict__ src, const int* __restrict__ dst,
                              int* __restrict__ cntS, int* __restrict__ cntD,
                              int* __restrict__ ranks) {
    int g = blockIdx.x * blockDim.x + threadIdx.x;
    int e0 = g * 8;
    if (e0 >= NEDGE) return;
    int4 s0 = *reinterpret_cast<const int4*>(src + e0);
    int4 s1 = *reinterpret_cast<const int4*>(src + e0 + 4);
    int4 d0 = *reinterpret_cast<const int4*>(dst + e0);
    int4 d1 = *reinterpret_cast<const int4*>(dst + e0 + 4);
    int rS0 = atomicAdd(&cntS[s0.x], 1);
    int rS1 = atomicAdd(&cntS[s0.y], 1);
    int rS2 = atomicAdd(&cntS[s0.z], 1);
    int rS3 = atomicAdd(&cntS[s0.w], 1);
    int rS4 = atomicAdd(&cntS[s1.x], 1);
    int rS5 = atomicAdd(&cntS[s1.y], 1);
    int rS6 = atomicAdd(&cntS[s1.z], 1);
    int rS7 = atomicAdd(&cntS[s1.w], 1);
    int rD0 = atomicAdd(&cntD[d0.x], 1);
    int rD1 = atomicAdd(&cntD[d0.y], 1);
    int rD2 = atomicAdd(&cntD[d0.z], 1);
    int rD3 = atomicAdd(&cntD[d0.w], 1);
    int rD4 = atomicAdd(&cntD[d1.x], 1);
    int rD5 = atomicAdd(&cntD[d1.y], 1);
    int rD6 = atomicAdd(&cntD[d1.z], 1);
    int rD7 = atomicAdd(&cntD[d1.w], 1);
    int4 o0, o1;
    o0.x = (rD0 << 16) | rS0; o0.y = (rD1 << 16) | rS1;
    o0.z = (rD2 << 16) | rS2; o0.w = (rD3 << 16) | rS3;
    o1.x = (rD4 << 16) | rS4; o1.y = (rD5 << 16) | rS5;
    o1.z = (rD6 << 16) | rS6; o1.w = (rD7 << 16) | rS7;
    *reinterpret_cast<int4*>(ranks + e0)     = o0;
    *reinterpret_cast<int4*>(ranks + e0 + 4) = o1;
}

// fused hierarchical exclusive scan over BOTH cnt arrays
__global__ void scanA2_kernel(const int* __restrict__ cntS, const int* __restrict__ cntD,
                              int* __restrict__ bsum) {
    __shared__ int lds[256];
    int half = (blockIdx.x >= NBLK) ? 1 : 0;
    int blk  = blockIdx.x - half * NBLK;
    const int* cnt = half ? cntD : cntS;
    int i = blk * 256 + threadIdx.x;
    int v = (i < NNODES) ? cnt[i] : 0;
    lds[threadIdx.x] = v;
    __syncthreads();
    for (int d = 128; d > 0; d >>= 1) {
        if (threadIdx.x < d) lds[threadIdx.x] += lds[threadIdx.x + d];
        __syncthreads();
    }
    if (threadIdx.x == 0) bsum[half * 256 + blk] = lds[0];
}

__global__ void scanB2_kernel(const int* __restrict__ bsum, int* __restrict__ boff) {
    __shared__ int lds[256];
    for (int half = 0; half < 2; ++half) {
        int v = (threadIdx.x < NBLK) ? bsum[half * 256 + threadIdx.x] : 0;
        lds[threadIdx.x] = v;
        __syncthreads();
        for (int d = 1; d < 256; d <<= 1) {
            int t = (threadIdx.x >= d) ? lds[threadIdx.x - d] : 0;
            __syncthreads();
            lds[threadIdx.x] += t;
            __syncthreads();
        }
        boff[half * 256 + threadIdx.x] = lds[threadIdx.x] - v;   // exclusive
        __syncthreads();
    }
}

__global__ void scanC2_kernel(const int* __restrict__ cntS, const int* __restrict__ cntD,
                              const int* __restrict__ boff,
                              int* __restrict__ offsS, int* __restrict__ offsD) {
    __shared__ int lds[256];
    int half = (blockIdx.x >= NBLK) ? 1 : 0;
    int blk  = blockIdx.x - half * NBLK;
    const int* cnt = half ? cntD : cntS;
    int* offs = half ? offsD : offsS;
    int i = blk * 256 + threadIdx.x;
    int v = (i < NNODES) ? cnt[i] : 0;
    lds[threadIdx.x] = v;
    __syncthreads();
    for (int d = 1; d < 256; d <<= 1) {
        int t = (threadIdx.x >= d) ? lds[threadIdx.x - d] : 0;
        __syncthreads();
        lds[threadIdx.x] += t;
        __syncthreads();
    }
    if (i < NNODES) offs[i] = boff[half * 256 + blk] + lds[threadIdx.x] - v;
}

// stream fill: 8 edges/thread, atomic-free (ranks precomputed)
__global__ void fill2_stream_kernel8(const int* __restrict__ src, const int* __restrict__ dst,
                                     const int* __restrict__ et, const int* __restrict__ ranks,
                                     const int* __restrict__ offsS, const int* __restrict__ offsD,
                                     int2* __restrict__ ebufSD) {
    int g = blockIdx.x * blockDim.x + threadIdx.x;
    int e0 = g * 8;
    if (e0 >= NEDGE) return;
    int4 s0 = *reinterpret_cast<const int4*>(src + e0);
    int4 s1 = *reinterpret_cast<const int4*>(src + e0 + 4);
    int4 d0 = *reinterpret_cast<const int4*>(dst + e0);
    int4 d1 = *reinterpret_cast<const int4*>(dst + e0 + 4);
    int4 t0 = *reinterpret_cast<const int4*>(et + e0);
    int4 t1 = *reinterpret_cast<const int4*>(et + e0 + 4);
    int4 r0 = *reinterpret_cast<const int4*>(ranks + e0);
    int4 r1 = *reinterpret_cast<const int4*>(ranks + e0 + 4);
    int s[8] = {s0.x, s0.y, s0.z, s0.w, s1.x, s1.y, s1.z, s1.w};
    int d[8] = {d0.x, d0.y, d0.z, d0.w, d1.x, d1.y, d1.z, d1.w};
    int t[8] = {t0.x, t0.y, t0.z, t0.w, t1.x, t1.y, t1.z, t1.w};
    int r[8] = {r0.x, r0.y, r0.z, r0.w, r1.x, r1.y, r1.z, r1.w};
    int oS[8], oD[8];
    #pragma unroll
    for (int i = 0; i < 8; ++i) oS[i] = offsS[s[i]];
    #pragma unroll
    for (int i = 0; i < 8; ++i) oD[i] = offsD[d[i]];
    #pragma unroll
    for (int i = 0; i < 8; ++i) {
        int spos = oS[i] + (r[i] & 0xFFFF);
        int slot = oD[i] + (r[i] >> 16);
        ebufSD[spos] = make_int2((t[i] << 25) | slot, (t[i] << 16) | d[i]);
    }
}

// atomic (fallback) mode, rank-based
__global__ void fill2_atomic_kernel(const int* __restrict__ src, const int* __restrict__ dst,
                                    const int* __restrict__ et, const int* __restrict__ ranks,
                                    const int* __restrict__ offsS, const int* __restrict__ offsD,
                                    int* __restrict__ ebufS, int* __restrict__ ebufD) {
    int e = blockIdx.x * blockDim.x + threadIdx.x;
    if (e < NEDGE) {
        int s = src[e], d = dst[e], t = et[e];
        int r = ranks[e];
        ebufD[offsD[d] + (r >> 16)]   = (t << 16) | s;
        ebufS[offsS[s] + (r & 0xFFFF)] = (t << 16) | d;
    }
}

// ---------------- weight expansion ----------------

__global__ void wexpand2_kernel(const float* __restrict__ att, const float* __restrict__ basis,
                                float* __restrict__ w2t) {
    int idx = blockIdx.x * blockDim.x + threadIdx.x;
    if (idx >= NREL * 256) return;
    int r = idx >> 8, t = idx & 255, o = t >> 5, i = t & 31;
    float s = 0.f;
    #pragma unroll
    for (int b = 0; b < NB; ++b) s += att[r * NB + b] * basis[b * 256 + i * 8 + o];
    w2t[r * 256 + o * 32 + i] = s;
}

__global__ void wexpand2h_kernel(const float* __restrict__ att, const float* __restrict__ basis,
                                 unsigned short* __restrict__ w2h) {
    int idx = blockIdx.x * blockDim.x + threadIdx.x;
    if (idx >= NREL * W2P) return;
    int r = idx / W2P, t = idx - r * W2P;
    int o = t / 40, i = t - o * 40;
    float s = 0.f;
    if (o < 8 && i < 32) {
        #pragma unroll
        for (int b = 0; b < NB; ++b) s += att[r * NB + b] * basis[b * 256 + i * 8 + o];
    }
    w2h[idx] = __half_as_ushort(__float2half_rn(s));
}

__global__ void wexpand3_kernel(const float* __restrict__ att, const float* __restrict__ basis,
                                float* __restrict__ w3) {
    int idx = blockIdx.x * blockDim.x + threadIdx.x;
    if (idx >= NREL * 8) return;
    int r = idx >> 3, i = idx & 7;
    float s = 0.f;
    #pragma unroll
    for (int b = 0; b < NB; ++b) s += att[r * NB + b] * basis[b * 8 + i];
    w3[idx] = s;
}

// ---------------- layer 1, stream path (fp16 fdot2) ----------------

__global__ void layer1_scatter_stream_kernel(const int2* __restrict__ ebufSD,
                                             const int* __restrict__ offsS,
                                             const int* __restrict__ cntS,
                                             const float* __restrict__ att1,
                                             const float* __restrict__ basis1,
                                             unsigned short* __restrict__ msgh) {
    __shared__ unsigned att_lds[NREL * 16];   // [r][16] half2-packed, pair 15 = 0
    for (int i = threadIdx.x; i < NREL * 16; i += 256) {
        int r = i >> 4, j = i & 15;
        float lo = (2 * j     < NB) ? att1[r * NB + 2 * j]     : 0.f;
        float hi = (2 * j + 1 < NB) ? att1[r * NB + 2 * j + 1] : 0.f;
        att_lds[i] = pack2h(lo, hi);
    }
    __syncthreads();
    int wave = threadIdx.x >> 6, lane = threadIdx.x & 63;
    int s = blockIdx.x * 4 + wave;           // NNODES % 4 == 0
    int o = lane & 31, half = lane >> 5;
    int off = offsS[s], c = cntS[s];
    if (c == 0) return;
    float Bf[NB];
    const float* bp = basis1 + (size_t)s * 32 + o;
    #pragma unroll
    for (int b = 0; b < NB; ++b) Bf[b] = bp[(size_t)b * (NNODES * 32)];
    unsigned B2[16];
    #pragma unroll
    for (int q = 0; q < 15; ++q) B2[q] = pack2h(Bf[2 * q], Bf[2 * q + 1]);
    B2[15] = 0u;
    for (int k = half; k < c; k += 2) {
        unsigned p = (unsigned)ebufSD[off + k].x;
        int slot = p & 0x01FFFFFF;
        int et   = p >> 25;
        const uint4* ar = (const uint4*)(att_lds + et * 16);
        float m0 = 0.f, m1 = 0.f, m2 = 0.f, m3 = 0.f;
        #pragma unroll
        for (int q = 0; q < 4; ++q) {
            uint4 w = ar[q];
            m0 = fdot2f(w.x, B2[q * 4 + 0], m0);
            m1 = fdot2f(w.y, B2[q * 4 + 1], m1);
            m2 = fdot2f(w.z, B2[q * 4 + 2], m2);
            m3 = fdot2f(w.w, B2[q * 4 + 3], m3);
        }
        float m = (m0 + m1) + (m2 + m3);
        float mo = __shfl_xor(m, 1);
        if ((o & 1) == 0) {
            __half2 h;
            h.x = __float2half_rn(m);
            h.y = __float2half_rn(mo);
            *reinterpret_cast<__half2*>(msgh + (size_t)slot * 32 + o) = h;
        }
    }
}

// reduce: 8 slots in flight, 8B loads/lane, float4 store
__global__ void layer1_reduce_kernel(const unsigned short* __restrict__ msgh,
                                     const int* __restrict__ offsD, const int* __restrict__ cntD,
                                     const float* __restrict__ root1,
                                     const float* __restrict__ bias1,
                                     float* __restrict__ x1) {
    int wave = threadIdx.x >> 6, lane = threadIdx.x & 63;
    int n = blockIdx.x * 4 + wave;
    int o4 = (lane & 7) * 4, grp = lane >> 3;
    int off = offsD[n], c = cntD[n];
    float a0 = 0.f, a1 = 0.f, a2 = 0.f, a3 = 0.f;
    for (int k = grp; k < c; k += 8) {
        uint2 u = *reinterpret_cast<const uint2*>(msgh + (size_t)(off + k) * 32 + o4);
        __half2 h0 = *reinterpret_cast<__half2*>(&u.x);
        __half2 h1 = *reinterpret_cast<__half2*>(&u.y);
        float2 f0 = __half22float2(h0), f1 = __half22float2(h1);
        a0 += f0.x; a1 += f0.y; a2 += f1.x; a3 += f1.y;
    }
    a0 += __shfl_xor(a0, 8);  a1 += __shfl_xor(a1, 8);  a2 += __shfl_xor(a2, 8);  a3 += __shfl_xor(a3, 8);
    a0 += __shfl_xor(a0, 16); a1 += __shfl_xor(a1, 16); a2 += __shfl_xor(a2, 16); a3 += __shfl_xor(a3, 16);
    a0 += __shfl_xor(a0, 32); a1 += __shfl_xor(a1, 32); a2 += __shfl_xor(a2, 32); a3 += __shfl_xor(a3, 32);
    if (grp == 0) {
        float inv = 1.0f / fmaxf((float)c, 1.0f);
        size_t base = (size_t)n * 32 + o4;
        float4 r = *reinterpret_cast<const float4*>(root1 + base);
        float4 v;
        v.x = fmaxf(a0 * inv + r.x + bias1[o4],     0.f);
        v.y = fmaxf(a1 * inv + r.y + bias1[o4 + 1], 0.f);
        v.z = fmaxf(a2 * inv + r.z + bias1[o4 + 2], 0.f);
        v.w = fmaxf(a3 * inv + r.w + bias1[o4 + 3], 0.f);
        *reinterpret_cast<float4*>(x1 + base) = v;
    }
}

// ---------------- layer 1, atomic fallback ----------------

__global__ void layer1_scatter_kernel(const int* __restrict__ ebufS, const int* __restrict__ offsS,
                                      const int* __restrict__ cntS, const float* __restrict__ att1,
                                      const float* __restrict__ basis1, float* __restrict__ x1acc) {
    int wave = threadIdx.x >> 6, lane = threadIdx.x & 63;
    int s = blockIdx.x * 4 + wave;
    int o = lane & 31, half = lane >> 5;
    int off = offsS[s], c = cntS[s];
    if (c == 0) return;
    float B[NB];
    const float* bp = basis1 + (size_t)s * 32 + o;
    #pragma unroll
    for (int b = 0; b < NB; ++b) B[b] = bp[(size_t)b * (NNODES * 32)];
    for (int k = half; k < c; k += 2) {
        int p  = ebufS[off + k];
        int d  = p & 0xFFFF, et = p >> 16;
        float attv = (o < NB) ? att1[et * NB + o] : 0.f;
        float m = 0.f;
        #pragma unroll
        for (int b = 0; b < NB; ++b) {
            float a = __shfl(attv, (lane & 32) + b);
            m = fmaf(a, B[b], m);
        }
        atomicAdd(&x1acc[(size_t)d * 32 + o], m);
    }
}

__global__ void layer1_finalize_kernel(const int* __restrict__ cntD,
                                       const float* __restrict__ root1,
                                       const float* __restrict__ bias1,
                                       float* __restrict__ x1) {
    int i = blockIdx.x * 256 + threadIdx.x;
    if (i >= NNODES * 32) return;
    int n = i >> 5, o = i & 31;
    float c = (float)cntD[n];
    float v = x1[i] / fmaxf(c, 1.0f) + root1[i] + bias1[o];
    x1[i] = fmaxf(v, 0.0f);
}

// ---------------- layer 2: src-major, LDS fp16 weights, atomic accumulate ----------------

__global__ void layer2_src_atomic_kernel(const int2* __restrict__ ebufSD,
                                         const int* __restrict__ offsS, const int* __restrict__ cntS,
                                         const float* __restrict__ x1,
                                         const unsigned short* __restrict__ w2h,
                                         float* __restrict__ x2acc) {
    __shared__ unsigned short w2l[NREL * W2P];   // 45,920 B
    for (int i = threadIdx.x; i < NREL * W2P; i += 1024) w2l[i] = w2h[i];
    __syncthreads();
    int wave = threadIdx.x >> 6, lane = threadIdx.x & 63;
    int s = blockIdx.x * 16 + wave;          // NNODES % 16 == 0
    int o = lane & 7, grp = lane >> 3;
    int off = offsS[s], c = cntS[s];
    if (c == 0) return;
    float2 xf[16];
    const float2* xp2 = (const float2*)(x1 + (size_t)s * 32);
    #pragma unroll
    for (int i = 0; i < 16; ++i) xf[i] = xp2[i];
    for (int k0 = 0; k0 < c; k0 += 8) {
        int kk = k0 + grp;
        if (kk < c) {
            int p = ebufSD[off + kk].y;
            int d = p & 0xFFFF, et = p >> 16;
            const unsigned short* wp = w2l + et * W2P + o * 40;
            float a0 = 0.f, a1 = 0.f, a2 = 0.f, a3 = 0.f;
            #pragma unroll
            for (int q = 0; q < 4; ++q) {
                uint4 wv = *reinterpret_cast<const uint4*>(wp + q * 8);
                __half2 h; float2 f;
                h = *reinterpret_cast<const __half2*>(&wv.x); f = __half22float2(h);
                a0 = fmaf(xf[q * 4 + 0].x, f.x, a0); a0 = fmaf(xf[q * 4 + 0].y, f.y, a0);
                h = *reinterpret_cast<const __half2*>(&wv.y); f = __half22float2(h);
                a1 = fmaf(xf[q * 4 + 1].x, f.x, a1); a1 = fmaf(xf[q * 4 + 1].y, f.y, a1);
                h = *reinterpret_cast<const __half2*>(&wv.z); f = __half22float2(h);
                a2 = fmaf(xf[q * 4 + 2].x, f.x, a2); a2 = fmaf(xf[q * 4 + 2].y, f.y, a2);
                h = *reinterpret_cast<const __half2*>(&wv.w); f = __half22float2(h);
                a3 = fmaf(xf[q * 4 + 3].x, f.x, a3); a3 = fmaf(xf[q * 4 + 3].y, f.y, a3);
            }
            float acc = (a0 + a1) + (a2 + a3);
            atomicAdd(&x2acc[(size_t)d * 8 + o], acc);
        }
    }
}

__global__ void layer2_finalize_kernel(const int* __restrict__ cntD,
                                       const float* __restrict__ x1,
                                       const float* __restrict__ root2,
                                       const float* __restrict__ bias2,
                                       float* __restrict__ x2) {
    int t = blockIdx.x * 256 + threadIdx.x;
    if (t >= NNODES * 8) return;
    int n = t >> 3, o = t & 7;
    float self = 0.f;
    const float* xn = x1 + (size_t)n * 32;
    #pragma unroll
    for (int i = 0; i < 32; ++i) self = fmaf(xn[i], root2[i * 8 + o], self);
    float c = (float)cntD[n];
    float v = x2[t] / fmaxf(c, 1.0f) + self + bias2[o];
    x2[t] = fmaxf(v, 0.0f);
}

// ---------------- layer 3: src-major, LDS weights, atomic accumulate into d_out ----------------

__global__ void layer3_src_atomic_kernel(const int2* __restrict__ ebufSD,
                                         const int* __restrict__ offsS, const int* __restrict__ cntS,
                                         const float* __restrict__ x2, const float* __restrict__ w3,
                                         float* __restrict__ outacc) {
    __shared__ float w3l[NREL * 8];
    for (int i = threadIdx.x; i < NREL * 8; i += 256) w3l[i] = w3[i];
    __syncthreads();
    int wave = threadIdx.x >> 6, lane = threadIdx.x & 63;
    int s = blockIdx.x * 4 + wave;
    int off = offsS[s], c = cntS[s];
    if (c == 0) return;
    const float4* xp = (const float4*)(x2 + (size_t)s * 8);
    float4 a0 = xp[0], a1 = xp[1];
    for (int k = lane; k < c; k += 64) {
        int p = ebufSD[off + k].y;
        int d = p & 0xFFFF, et = p >> 16;
        const float4* wp = (const float4*)(w3l + et * 8);
        float4 b0 = wp[0], b1 = wp[1];
        float m = a0.x * b0.x + a0.y * b0.y + a0.z * b0.z + a0.w * b0.w
                + a1.x * b1.x + a1.y * b1.y + a1.z * b1.z + a1.w * b1.w;
        atomicAdd(&outacc[d], m);
    }
}

__global__ void layer3_finalize_kernel(const int* __restrict__ cntD,
                                       const float* __restrict__ x2,
                                       const float* __restrict__ root3,
                                       const float* __restrict__ bias3,
                                       float* __restrict__ out) {
    int n = blockIdx.x * 256 + threadIdx.x;
    if (n >= NNODES) return;
    float self = 0.f;
    const float* xn = x2 + (size_t)n * 8;
    #pragma unroll
    for (int i = 0; i < 8; ++i) self = fmaf(xn[i], root3[i], self);
    float c = (float)cntD[n];
    out[n] = out[n] / fmaxf(c, 1.0f) + self + bias3[0];
}

// ---------------- legacy per-node layers 2/3 (fallback, atomic-mode only) ----------------

__global__ void layer2_kernel(const int* __restrict__ ebufD, const int* __restrict__ offsD,
                              const int* __restrict__ cntD,
                              const float* __restrict__ x1, const float* __restrict__ w2t,
                              const float* __restrict__ root2, const float* __restrict__ bias2,
                              float* __restrict__ x2) {
    int wave = threadIdx.x >> 6, lane = threadIdx.x & 63;
    int n = blockIdx.x * 4 + wave;
    int o = lane & 7, slot = lane >> 3;
    int off = offsD[n], c = cntD[n];
    float acc = 0.f;
    for (int k0 = 0; k0 < c; k0 += 8) {
        int kk = k0 + slot;
        if (kk < c) {
            int packed = ebufD[off + kk];
            int src = packed & 0xFFFF, et = packed >> 16;
            const float4* xp = (const float4*)(x1 + (size_t)src * 32);
            const float4* wp = (const float4*)(w2t + et * 256 + o * 32);
            #pragma unroll
            for (int i = 0; i < 8; ++i) {
                float4 xv = xp[i], wv = wp[i];
                acc += xv.x * wv.x + xv.y * wv.y + xv.z * wv.z + xv.w * wv.w;
            }
        }
    }
    #pragma unroll
    for (int d = 8; d < 64; d <<= 1) acc += __shfl_xor(acc, d);
    if (lane < 8) {
        float self = 0.f;
        const float* xn = x1 + (size_t)n * 32;
        #pragma unroll
        for (int i = 0; i < 32; ++i) self += xn[i] * root2[i * 8 + o];
        float v = acc / fmaxf((float)c, 1.0f) + self + bias2[o];
        x2[(size_t)n * 8 + o] = fmaxf(v, 0.0f);
    }
}

__global__ void layer3_kernel(const int* __restrict__ ebufD, const int* __restrict__ offsD,
                              const int* __restrict__ cntD,
                              const float* __restrict__ x2, const float* __restrict__ w3,
                              const float* __restrict__ root3, const float* __restrict__ bias3,
                              float* __restrict__ out) {
    int wave = threadIdx.x >> 6, lane = threadIdx.x & 63;
    int n = blockIdx.x * 4 + wave;
    int off = offsD[n], c = cntD[n];
    float acc = 0.f;
    for (int k = lane; k < c; k += 64) {
        int packed = ebufD[off + k];
        int src = packed & 0xFFFF, et = packed >> 16;
        const float4* xp = (const float4*)(x2 + src * 8);
        const float4* wp = (const float4*)(w3 + et * 8);
        float4 a0 = xp[0], a1 = xp[1], b0 = wp[0], b1 = wp[1];
        acc += a0.x * b0.x + a0.y * b0.y + a0.z * b0.z + a0.w * b0.w
             + a1.x * b1.x + a1.y * b1.y + a1.z * b1.z + a1.w * b1.w;
    }
    #pragma unroll
    for (int d = 1; d < 64; d <<= 1) acc += __shfl_xor(acc, d);
    if (lane == 0) {
        float self = 0.f;
        const float* xn = x2 + (size_t)n * 8;
        #pragma unroll
        for (int i = 0; i < 8; ++i) self += xn[i] * root3[i];
        out[n] = acc / fmaxf((float)c, 1.0f) + self + bias3[0];
    }
}

// ---------------- launch ----------------

extern "C" void kernel_launch(void* const* d_in, const int* in_sizes, int n_in,
                              void* d_out, int out_size, void* d_ws, size_t ws_size,
                              hipStream_t stream) {
    const int*   edge_index = (const int*)  d_in[0];
    const int*   edge_type  = (const int*)  d_in[1];
    const float* att1   = (const float*) d_in[2];
    const float* basis1 = (const float*) d_in[3];
    const float* root1  = (const float*) d_in[4];
    const float* bias1  = (const float*) d_in[5];
    const float* att2   = (const float*) d_in[6];
    const float* basis2 = (const float*) d_in[7];
    const float* root2  = (const float*) d_in[8];
    const float* bias2  = (const float*) d_in[9];
    const float* att3   = (const float*) d_in[10];
    const float* basis3 = (const float*) d_in[11];
    const float* root3  = (const float*) d_in[12];
    const float* bias3  = (const float*) d_in[13];
    float* out = (float*)d_out;

    const int* srcArr = edge_index;
    const int* dstArr = edge_index + NEDGE;

    char* ws = (char*)d_ws;
    int*   cntS   = (int*)(ws + 0);              // 240,000
    int*   cntD   = (int*)(ws + 240128);         // 240,000
    int*   offsS  = (int*)(ws + 480256);         // 240,000
    int*   offsD  = (int*)(ws + 720384);         // 240,000
    int*   bsum   = (int*)(ws + 960512);         // 2,048
    int*   boff   = (int*)(ws + 962560);         // 2,048
    int*   ebufS  = (int*)(ws + 1442816);        // 7,680,000 (fallback)
    int*   ebufD  = (int*)(ws + 9122816);        // 7,680,000 (fallback)
    int2*  ebufSD = (int2*)(ws + 1442816);       // 15,360,000 (stream: combined)
    float* w2t    = (float*)(ws + 16802816);     // 71,680 (fallback)
    float* w3     = (float*)(ws + 16874496);     // 2,240
    unsigned short* w2h = (unsigned short*)(ws + 16876800);  // 45,920
    float* x1     = (float*)(ws + 16923648);     // 7,680,000
    int*   ranks  = (int*)(ws + 16923648);       // aliases x1 (dead until layer1_reduce)
    float* x2     = (float*)(ws + 24603648);     // 1,920,000  (acc then final, in place)
    unsigned short* msgh = (unsigned short*)(ws + 26523648); // 122,880,000 -> end 149,403,648
    const bool use_stream = ws_size >= 149403648ULL;

    // zero histograms + accumulators
    hipMemsetAsync(ws, 0, 480128, stream);              // cntS + cntD
    hipMemsetAsync((void*)x2, 0, 1920000, stream);      // x2 accumulator
    hipMemsetAsync(d_out, 0, NNODES * 4, stream);       // out accumulator

    // CSR build: 8 edges/thread counting, fused scans, atomic-free fill
    hist2_kernel8<<<(NEDGE / 8 + 255) / 256, 256, 0, stream>>>(srcArr, dstArr, cntS, cntD, ranks);
    scanA2_kernel<<<2 * NBLK, 256, 0, stream>>>(cntS, cntD, bsum);
    scanB2_kernel<<<1, 256, 0, stream>>>(bsum, boff);
    scanC2_kernel<<<2 * NBLK, 256, 0, stream>>>(cntS, cntD, boff, offsS, offsD);
    if (use_stream) {
        fill2_stream_kernel8<<<(NEDGE / 8 + 255) / 256, 256, 0, stream>>>(srcArr, dstArr, edge_type,
                                                                          ranks, offsS, offsD, ebufSD);
    } else {
        fill2_atomic_kernel<<<NEDGE / 256, 256, 0, stream>>>(srcArr, dstArr, edge_type, ranks,
                                                             offsS, offsD, ebufS, ebufD);
    }

    // weight expansion
    wexpand2h_kernel<<<(NREL * W2P + 255) / 256, 256, 0, stream>>>(att2, basis2, w2h);
    wexpand3_kernel<<<(NREL * 8 + 255) / 256, 256, 0, stream>>>(att3, basis3, w3);
    if (!use_stream) {
        wexpand2_kernel<<<(NREL * 256 + 255) / 256, 256, 0, stream>>>(att2, basis2, w2t);
    }

    // layer 1
    if (use_stream) {
        layer1_scatter_stream_kernel<<<NNODES / 4, 256, 0, stream>>>(ebufSD, offsS, cntS,
                                                                     att1, basis1, msgh);
        layer1_reduce_kernel<<<NNODES / 4, 256, 0, stream>>>(msgh, offsD, cntD, root1, bias1, x1);
    } else {
        hipMemsetAsync((void*)x1, 0, 7680000, stream);
        layer1_scatter_kernel<<<NNODES / 4, 256, 0, stream>>>(ebufS, offsS, cntS, att1, basis1, x1);
        layer1_finalize_kernel<<<(NNODES * 32) / 256, 256, 0, stream>>>(cntD, root1, bias1, x1);
    }

    // layers 2, 3
    if (use_stream) {
        layer2_src_atomic_kernel<<<NNODES / 16, 1024, 0, stream>>>(ebufSD, offsS, cntS, x1, w2h, x2);
        layer2_finalize_kernel<<<(NNODES * 8 + 255) / 256, 256, 0, stream>>>(cntD, x1, root2, bias2, x2);
        layer3_src_atomic_kernel<<<NNODES / 4, 256, 0, stream>>>(ebufSD, offsS, cntS, x2, w3, out);
        layer3_finalize_kernel<<<(NNODES + 255) / 256, 256, 0, stream>>>(cntD, x2, root3, bias3, out);
    } else {
        layer2_kernel<<<NNODES / 4, 256, 0, stream>>>(ebufD, offsD, cntD, x1, w2t, root2, bias2, x2);
        layer3_kernel<<<NNODES / 4, 256, 0, stream>>>(ebufD, offsD, cntD, x2, w3, root3, bias3, out);
    }
}